// Round 3
// baseline (468.663 us; speedup 1.0000x reference)
//
#include <hip/hip_runtime.h>
#include <hip/hip_bf16.h>

#define N_ 16384
#define D_ 512
#define BM 256
#define BN 256
#define BK 64
#define NT (D_ / BK)    // 8 K-tiles
#define NBLK (N_ / BM)  // 64 blocks per dim
#define BUFB 32768      // bytes per LDS buffer (256*64*2)

typedef __attribute__((ext_vector_type(8))) __bf16 bf16x8;
typedef __attribute__((ext_vector_type(4))) float f32x4;

#define GLDS(gptr, lptr)                                                              \
  __builtin_amdgcn_global_load_lds((const __attribute__((address_space(1))) void*)(gptr), \
                                   (__attribute__((address_space(3))) void*)(lptr), 16, 0, 0)

__device__ inline unsigned short f2bf(float f) {
  __hip_bfloat16 h = __float2bfloat16(f);
  return *reinterpret_cast<unsigned short*>(&h);
}

// ---------------- fp32 -> bf16 convert (vectorized), optional scale fold ----------------
__global__ void cvt_bf16_kernel(const float* __restrict__ src,
                                unsigned short* __restrict__ dst, long n,
                                const float* __restrict__ scale_p) {
  const float s = scale_p ? scale_p[0] : 1.0f;
  long i = ((long)blockIdx.x * blockDim.x + threadIdx.x) * 8;
  const long stride = (long)gridDim.x * blockDim.x * 8;
  typedef __attribute__((ext_vector_type(8))) unsigned short us8;
  for (; i < n; i += stride) {
    const float4* sp = (const float4*)(src + i);
    float4 f0 = sp[0], f1 = sp[1];
    us8 v;
    v[0] = f2bf(f0.x * s); v[1] = f2bf(f0.y * s); v[2] = f2bf(f0.z * s); v[3] = f2bf(f0.w * s);
    v[4] = f2bf(f1.x * s); v[5] = f2bf(f1.y * s); v[6] = f2bf(f1.z * s); v[7] = f2bf(f1.w * s);
    *(us8*)(dst + i) = v;
  }
}

// ---------------- 256x256 double-buffered GEMM + row/col online-LSE partials ----------------
// T3+T4: counted vmcnt(8) keeps next-tile global_load_lds in flight across barriers.
// T2: R2-verified XOR swizzle (linear LDS dest + inverse-swizzled global src + XOR'd ds_read).
// T5: setprio around MFMA clusters. T1: XCD-bijective block swizzle (4096 % 8 == 0).
__global__ __launch_bounds__(512, 2)
void gemm_lse_kernel(const unsigned short* __restrict__ A,   // scale*img bf16 [N][D]
                     const unsigned short* __restrict__ B,   // txt bf16 [N][D]
                     float2* __restrict__ rowMS,  // [NBLK(colblk)][N] (max, sumexp)
                     float2* __restrict__ colMS,  // [NBLK(rowblk)][N]
                     float* __restrict__ diag) {
  __shared__ __align__(16) unsigned short As[2][BM][BK];  // 64 KiB
  __shared__ __align__(16) unsigned short Bs[2][BN][BK];  // 64 KiB

  const int t = threadIdx.x;
  const int l = t & 63;
  const int wid = t >> 6;   // 0..7
  const int wr = wid >> 2;  // 0..1 : wave rows [wr*128, +128)
  const int wc = wid & 3;   // 0..3 : wave cols [wc*64, +64)

  int id = blockIdx.x;
  id = (id & 7) * (NBLK * NBLK / 8) + (id >> 3);
  const int br = id / NBLK;
  const int bc = id % NBLK;

  // staging: thread t stages 4x16B per operand tile to LINEAR LDS byte t*16 + c*8192.
  // LDS row = c*64 + (t>>3); global source col inverse-swizzled (verified in R2).
  const int srow = t >> 3;                          // 0..63
  const int scol = (((t & 7) ^ (srow & 7)) << 3);   // elements

  const unsigned short* aBase = A + (size_t)(br * BM + srow) * D_ + scol;
  const unsigned short* bBase = B + (size_t)(bc * BN + srow) * D_ + scol;

  f32x4 acc[8][4];
#pragma unroll
  for (int m = 0; m < 8; ++m)
#pragma unroll
    for (int n = 0; n < 4; ++n) acc[m][n] = (f32x4)0.0f;

  const int swz = (l & 7) << 4;  // ds_read byte-XOR, row&7 == l&7
  const char* asb = (const char*)As;
  const char* bsb = (const char*)Bs;

#define STAGE(kt_, b_)                                              \
  {                                                                 \
    const unsigned short* ag_ = aBase + (kt_)*BK;                   \
    const unsigned short* bg_ = bBase + (kt_)*BK;                   \
    char* al_ = (char*)As + (b_)*BUFB + t * 16;                     \
    char* bl_ = (char*)Bs + (b_)*BUFB + t * 16;                     \
    _Pragma("unroll") for (int c_ = 0; c_ < 4; ++c_) {              \
      GLDS(ag_ + c_ * 64 * D_, al_ + c_ * 8192);                    \
      GLDS(bg_ + c_ * 64 * D_, bl_ + c_ * 8192);                    \
    }                                                               \
  }

  STAGE(0, 0);
  STAGE(1, 1);

#pragma unroll
  for (int kt = 0; kt < NT; ++kt) {
    const int b = kt & 1;
    // tile kt ready: own 8 loads of tile kt done; tile kt+1's 8 may stay in flight
    if (kt == NT - 1) { asm volatile("s_waitcnt vmcnt(0)" ::: "memory"); }
    else              { asm volatile("s_waitcnt vmcnt(8)" ::: "memory"); }
    __builtin_amdgcn_sched_barrier(0);
    __builtin_amdgcn_s_barrier();
    __builtin_amdgcn_sched_barrier(0);

#pragma unroll
    for (int kk = 0; kk < 2; ++kk) {
      const int cbk = kk * 64 + (l >> 4) * 16;  // byte-in-row pre-swizzle
      bf16x8 af[8], bfv[4];
#pragma unroll
      for (int m = 0; m < 8; ++m)
        af[m] = *(const bf16x8*)(asb + b * BUFB +
                                 (wr * 128 + m * 16 + (l & 15)) * 128 + (cbk ^ swz));
#pragma unroll
      for (int n = 0; n < 4; ++n)
        bfv[n] = *(const bf16x8*)(bsb + b * BUFB +
                                  (wc * 64 + n * 16 + (l & 15)) * 128 + (cbk ^ swz));
      __builtin_amdgcn_s_setprio(1);
#pragma unroll
      for (int m = 0; m < 8; ++m)
#pragma unroll
        for (int n = 0; n < 4; ++n)
          acc[m][n] = __builtin_amdgcn_mfma_f32_16x16x32_bf16(af[m], bfv[n], acc[m][n], 0, 0, 0);
      __builtin_amdgcn_s_setprio(0);
    }

    // drain own ds_reads before signaling; then stage tile kt+2 into freed buffer
    asm volatile("s_waitcnt lgkmcnt(0)" ::: "memory");
    __builtin_amdgcn_sched_barrier(0);
    __builtin_amdgcn_s_barrier();
    __builtin_amdgcn_sched_barrier(0);
    if (kt + 2 < NT) STAGE(kt + 2, b);
  }
#undef STAGE

  // ---- epilogue: diag, row/col online-LSE partials; reuse As as merge scratch ----
  float* rowb = (float*)As;            // [4][256][2] floats (8 KiB)
  float* colb = rowb + 4 * 256 * 2;    // [2][256][2] floats (4 KiB)

  if (br == bc) {
#pragma unroll
    for (int m = 0; m < 8; ++m)
#pragma unroll
      for (int n = 0; n < 4; ++n)
#pragma unroll
        for (int r = 0; r < 4; ++r) {
          const int row = wr * 128 + m * 16 + (l >> 4) * 4 + r;
          const int col = wc * 64 + n * 16 + (l & 15);
          if (row == col) diag[br * BM + row] = acc[m][n][r];
        }
  }

  // ROW pass: row = wr*128 + m*16 + (l>>4)*4 + r; its 64 cols = {n} x 16 lanes (l&15)
#pragma unroll
  for (int m = 0; m < 8; ++m) {
#pragma unroll
    for (int r = 0; r < 4; ++r) {
      float mx = fmaxf(fmaxf(acc[m][0][r], acc[m][1][r]), fmaxf(acc[m][2][r], acc[m][3][r]));
#pragma unroll
      for (int off = 1; off < 16; off <<= 1) mx = fmaxf(mx, __shfl_xor(mx, off, 64));
      float s = 0.f;
#pragma unroll
      for (int n = 0; n < 4; ++n) s += __expf(acc[m][n][r] - mx);
#pragma unroll
      for (int off = 1; off < 16; off <<= 1) s += __shfl_xor(s, off, 64);
      if ((l & 15) == 0) {
        const int row = wr * 128 + m * 16 + (l >> 4) * 4 + r;
        rowb[(wc * 256 + row) * 2 + 0] = mx;
        rowb[(wc * 256 + row) * 2 + 1] = s;
      }
    }
  }

  // COL pass: col = wc*64 + n*16 + (l&15); its 128 rows = {m,r} x 4 lane-groups (l>>4)
#pragma unroll
  for (int n = 0; n < 4; ++n) {
    float mx = -1e30f;
#pragma unroll
    for (int m = 0; m < 8; ++m)
#pragma unroll
      for (int r = 0; r < 4; ++r) mx = fmaxf(mx, acc[m][n][r]);
    mx = fmaxf(mx, __shfl_xor(mx, 16, 64));
    mx = fmaxf(mx, __shfl_xor(mx, 32, 64));
    float s = 0.f;
#pragma unroll
    for (int m = 0; m < 8; ++m)
#pragma unroll
      for (int r = 0; r < 4; ++r) s += __expf(acc[m][n][r] - mx);
    s += __shfl_xor(s, 16, 64);
    s += __shfl_xor(s, 32, 64);
    if ((l >> 4) == 0) {
      const int col = wc * 64 + n * 16 + l;
      colb[(wr * 256 + col) * 2 + 0] = mx;
      colb[(wr * 256 + col) * 2 + 1] = s;
    }
  }
  __syncthreads();

  // merge wave-halves, write partials (coalesced float2)
  if (t < 256) {
    float mm = -1e30f, ss = 0.f;
#pragma unroll
    for (int w = 0; w < 4; ++w) {
      float m0 = rowb[(w * 256 + t) * 2 + 0], s0 = rowb[(w * 256 + t) * 2 + 1];
      float nm = fmaxf(mm, m0);
      ss = ss * __expf(mm - nm) + s0 * __expf(m0 - nm);
      mm = nm;
    }
    rowMS[(size_t)bc * N_ + br * BM + t] = make_float2(mm, ss);
  } else {
    const int c = t - 256;
    float mm = -1e30f, ss = 0.f;
#pragma unroll
    for (int w = 0; w < 2; ++w) {
      float m0 = colb[(w * 256 + c) * 2 + 0], s0 = colb[(w * 256 + c) * 2 + 1];
      float nm = fmaxf(mm, m0);
      ss = ss * __expf(mm - nm) + s0 * __expf(m0 - nm);
      mm = nm;
    }
    colMS[(size_t)br * N_ + bc * BN + c] = make_float2(mm, ss);
  }
}

// ---------------- merge partials -> per-row/col LSE -> partial sums ----------------
__global__ void reduce1_kernel(const float2* __restrict__ rowMS,
                               const float2* __restrict__ colMS,
                               const float* __restrict__ diag,
                               float* __restrict__ partials) {
  const int tid = blockIdx.x * blockDim.x + threadIdx.x;  // 0..32767
  float m = -1e30f, s = 0.f;
  if (tid < N_) {
    const int r = tid;
    for (int cb = 0; cb < NBLK; ++cb) {
      float2 p = rowMS[(size_t)cb * N_ + r];
      float nm = fmaxf(m, p.x);
      s = s * __expf(m - nm) + p.y * __expf(p.x - nm);
      m = nm;
    }
    m = m + logf(s) - diag[r];
  } else {
    const int c = tid - N_;
    for (int rb = 0; rb < NBLK; ++rb) {
      float2 p = colMS[(size_t)rb * N_ + c];
      float nm = fmaxf(m, p.x);
      s = s * __expf(m - nm) + p.y * __expf(p.x - nm);
      m = nm;
    }
    m = m + logf(s) - diag[c];
  }
  float val = m;
#pragma unroll
  for (int off = 1; off < 64; off <<= 1) val += __shfl_xor(val, off, 64);
  __shared__ float red[4];
  if ((threadIdx.x & 63) == 0) red[threadIdx.x >> 6] = val;
  __syncthreads();
  if (threadIdx.x == 0) partials[blockIdx.x] = red[0] + red[1] + red[2] + red[3];
}

__global__ void reduce2_kernel(const float* __restrict__ partials, float* __restrict__ out) {
  const int t = threadIdx.x;  // 64 threads
  float v = partials[t] + partials[t + 64];
#pragma unroll
  for (int off = 1; off < 64; off <<= 1) v += __shfl_xor(v, off, 64);
  if (t == 0) out[0] = v * (1.0f / (2.0f * (float)N_));
}

extern "C" void kernel_launch(void* const* d_in, const int* in_sizes, int n_in,
                              void* d_out, int out_size, void* d_ws, size_t ws_size,
                              hipStream_t stream) {
  const float* img = (const float*)d_in[0];
  const float* txt = (const float*)d_in[1];
  const float* scale = (const float*)d_in[2];
  float* out = (float*)d_out;

  char* ws = (char*)d_ws;
  size_t off = 0;
  unsigned short* imgB = (unsigned short*)(ws + off); off += (size_t)N_ * D_ * 2;
  unsigned short* txtB = (unsigned short*)(ws + off); off += (size_t)N_ * D_ * 2;
  float2* rowMS = (float2*)(ws + off); off += (size_t)NBLK * N_ * sizeof(float2);
  float2* colMS = (float2*)(ws + off); off += (size_t)NBLK * N_ * sizeof(float2);
  float* diag = (float*)(ws + off); off += (size_t)N_ * sizeof(float);
  float* partials = (float*)(ws + off); off += 128 * sizeof(float);
  (void)ws_size; (void)in_sizes; (void)n_in; (void)out_size;

  cvt_bf16_kernel<<<1024, 256, 0, stream>>>(img, imgB, (long)N_ * D_, scale);
  cvt_bf16_kernel<<<1024, 256, 0, stream>>>(txt, txtB, (long)N_ * D_, nullptr);
  gemm_lse_kernel<<<NBLK * NBLK, 512, 0, stream>>>(imgB, txtB, rowMS, colMS, diag);
  reduce1_kernel<<<(2 * N_) / 256, 256, 0, stream>>>(rowMS, colMS, diag, partials);
  reduce2_kernel<<<1, 64, 0, stream>>>(partials, out);
}